// Round 1
// baseline (454.705 us; speedup 1.0000x reference)
//
#include <hip/hip_runtime.h>
#include <math.h>

typedef unsigned short u16;
typedef __attribute__((ext_vector_type(8))) short bf16x8;   // 8 bf16 in 4 VGPRs
typedef __attribute__((ext_vector_type(4))) float f32x4;    // MFMA C/D

#define T_TOK 16384
#define NEXP 8

__device__ __forceinline__ u16 f2bf(float f) {
    union { float f; unsigned u; } v; v.f = f;
    unsigned u = v.u;
    return (u16)((u + 0x7fffu + ((u >> 16) & 1u)) >> 16);   // RNE
}

// ---------------- x fp32 -> bf16 ----------------
__global__ void cvt_x_kernel(const float* __restrict__ src, u16* __restrict__ dst, int n4) {
    int i = blockIdx.x * blockDim.x + threadIdx.x;
    int stride = gridDim.x * blockDim.x;
    for (; i < n4; i += stride) {
        float4 v = ((const float4*)src)[i];
        ushort4 o;
        o.x = f2bf(v.x); o.y = f2bf(v.y); o.z = f2bf(v.z); o.w = f2bf(v.w);
        ((ushort4*)dst)[i] = o;
    }
}

// ------------- weights: [Z][R][C] f32 -> [Z][C][R] bf16 (transpose+convert) -------------
__global__ void transpose_cvt_kernel(const float* __restrict__ src, u16* __restrict__ dst,
                                     int R, int C) {
    __shared__ float tile[32][33];
    int e  = blockIdx.z;
    int c0 = blockIdx.x * 32, r0 = blockIdx.y * 32;
    int tx = threadIdx.x & 31, ty = threadIdx.x >> 5;   // ty in 0..7
    const float* s = src + (size_t)e * R * C;
#pragma unroll
    for (int i = 0; i < 32; i += 8)
        tile[ty + i][tx] = s[(size_t)(r0 + ty + i) * C + (c0 + tx)];
    __syncthreads();
    u16* d = dst + (size_t)e * R * C;
#pragma unroll
    for (int i = 0; i < 32; i += 8)
        d[(size_t)(c0 + ty + i) * R + (r0 + tx)] = f2bf(tile[tx][ty + i]);
}

// ---------------- router: scores (fp64 acc), top-2, gates, per-expert lists ----------------
__global__ void router_kernel(const float* __restrict__ x, const float* __restrict__ Wg,
                              const float* __restrict__ bg, int* __restrict__ counts,
                              int* __restrict__ tokenlist, float* __restrict__ gatelist) {
    __shared__ float wg[512 * 8];
    int tid = threadIdx.x;
    for (int i = tid; i < 1024; i += 128)
        ((float4*)wg)[i] = ((const float4*)Wg)[i];
    __syncthreads();

    int t = blockIdx.x * 128 + tid;                 // 128 blocks x 128 threads = 16384
    const float* xr = x + (size_t)t * 512;
    double acc[8];
#pragma unroll
    for (int j = 0; j < 8; j++) acc[j] = 0.0;
    for (int k = 0; k < 512; k += 4) {
        float4 v = *(const float4*)(xr + k);
        float vv[4] = { v.x, v.y, v.z, v.w };
#pragma unroll
        for (int q = 0; q < 4; q++) {
#pragma unroll
            for (int j = 0; j < 8; j++)
                acc[j] += (double)vv[q] * (double)wg[(k + q) * 8 + j];
        }
    }
    double s[8];
#pragma unroll
    for (int j = 0; j < 8; j++) s[j] = acc[j] + (double)bg[j];
    // top-2, jax tie-break = lower index first (strict > keeps earliest max)
    int i0 = 0;
#pragma unroll
    for (int j = 1; j < 8; j++) if (s[j] > s[i0]) i0 = j;
    int i1 = (i0 == 0) ? 1 : 0;
#pragma unroll
    for (int j = 0; j < 8; j++) if (j != i0 && s[j] > s[i1]) i1 = j;
    float d  = expf((float)(s[i1] - s[i0]));        // <= 1
    float g0 = 1.f / (1.f + d);
    float g1 = d / (1.f + d);

    // wave-aggregated list build: 16 atomics per wave total
    int lane = tid & 63;
    unsigned long long lt = (1ull << lane) - 1ull;
    for (int j = 0; j < NEXP; j++) {
#pragma unroll
        for (int p = 0; p < 2; p++) {
            int   ej = p ? i1 : i0;
            float gj = p ? g1 : g0;
            unsigned long long m = __ballot(ej == j);
            if (m) {
                int leader = __ffsll((unsigned long long)m) - 1;
                int base = 0;
                if (lane == leader) base = atomicAdd(&counts[j], __popcll(m));
                base = __shfl(base, leader);
                if (ej == j) {
                    int slot = base + __popcll(m & lt);
                    tokenlist[j * T_TOK + slot] = t;
                    gatelist [j * T_TOK + slot] = gj;
                }
            }
        }
    }
}

// ---------------- fused expert MLP: GELU(Xg@W1+b1)@W2+b2, gated atomic scatter ----------------
// grid = 8 experts * 512 tiles, expert = blockIdx&7 (XCD L2 affinity), 512 thr = 8 waves,
// tile = 32 tokens. LDS: Xs 32x512 bf16 (32KB, XOR-swizzled) + Hs 32x768 bf16 (48KB, swizzled)
__global__ __launch_bounds__(512, 4) void expert_kernel(
    const u16* __restrict__ xb, const u16* __restrict__ W1t, const u16* __restrict__ W2t,
    const float* __restrict__ b1, const float* __restrict__ b2,
    const int* __restrict__ counts, const int* __restrict__ tokenlist,
    const float* __restrict__ gatelist, float* __restrict__ out)
{
    int e    = blockIdx.x & 7;
    int tile = blockIdx.x >> 3;
    int cnt  = counts[e];
    int row0 = tile * 32;
    if (row0 >= cnt) return;

    __shared__ __align__(16) char smem[81920];
    int tid = threadIdx.x;
    const int eT = e * T_TOK;

    // ---- stage gathered X tile into swizzled LDS ----
#pragma unroll
    for (int j = 0; j < 4; j++) {
        int chunk = tid + j * 512;            // 2048 chunks of 16B
        int row = chunk >> 6;                 // 64 chunks per 512-elem row
        int cc  = chunk & 63;
        int slot = row0 + row;
        int tok = (slot < cnt) ? tokenlist[eT + slot] : 0;
        uint4 v = *(const uint4*)(xb + (size_t)tok * 512 + cc * 8);
        int off = (row * 1024 + cc * 16) ^ ((row & 7) << 4);
        *(uint4*)(smem + off) = v;
    }
    __syncthreads();

    int lane = tid & 63;
    int w    = tid >> 6;
    int lr   = lane & 15;
    int lk   = (lane >> 4) * 8;

    // ---- phase 1: H[32][768] = GELU(X @ W1 + b1); wave w owns cols [w*96, w*96+96) ----
    f32x4 acc1[2][6];
#pragma unroll
    for (int mi = 0; mi < 2; mi++)
#pragma unroll
        for (int ni = 0; ni < 6; ni++)
            acc1[mi][ni] = (f32x4){0.f, 0.f, 0.f, 0.f};
    {
        const u16* w1base = W1t + (size_t)e * 768 * 512;  // [h][k]
        int n0 = w * 96;
        for (int kk = 0; kk < 512; kk += 32) {
            bf16x8 a[2], b[6];
#pragma unroll
            for (int mi = 0; mi < 2; mi++) {
                int row = mi * 16 + lr;
                int off = (row * 1024 + (kk + lk) * 2) ^ ((row & 7) << 4);
                a[mi] = *(const bf16x8*)(smem + off);
            }
#pragma unroll
            for (int ni = 0; ni < 6; ni++) {
                int n = n0 + ni * 16 + lr;
                b[ni] = *(const bf16x8*)(w1base + (size_t)n * 512 + kk + lk);
            }
#pragma unroll
            for (int mi = 0; mi < 2; mi++)
#pragma unroll
                for (int ni = 0; ni < 6; ni++)
                    acc1[mi][ni] = __builtin_amdgcn_mfma_f32_16x16x32_bf16(
                        a[mi], b[ni], acc1[mi][ni], 0, 0, 0);
        }
        // bias + exact GELU -> Hs (swizzled)
#pragma unroll
        for (int ni = 0; ni < 6; ni++) {
            int col = n0 + ni * 16 + lr;
            float bb = b1[e * 768 + col];
#pragma unroll
            for (int mi = 0; mi < 2; mi++) {
#pragma unroll
                for (int r = 0; r < 4; r++) {
                    int row = mi * 16 + (lane >> 4) * 4 + r;
                    float h  = acc1[mi][ni][r] + bb;
                    float gl = 0.5f * h * (1.f + erff(h * 0.70710678118654752f));
                    int off = (row * 1536 + col * 2) ^ ((row & 7) << 4);
                    *(u16*)(smem + 32768 + off) = f2bf(gl);
                }
            }
        }
    }
    __syncthreads();

    // ---- phase 2: O[32][512] = H @ W2; wave w owns cols [w*64, w*64+64) ----
    f32x4 acc2[2][4];
#pragma unroll
    for (int mi = 0; mi < 2; mi++)
#pragma unroll
        for (int ni = 0; ni < 4; ni++)
            acc2[mi][ni] = (f32x4){0.f, 0.f, 0.f, 0.f};
    {
        const u16* w2base = W2t + (size_t)e * 512 * 768;  // [o][k]
        int c0 = w * 64;
        for (int kk = 0; kk < 768; kk += 32) {
            bf16x8 a[2], b[4];
#pragma unroll
            for (int mi = 0; mi < 2; mi++) {
                int row = mi * 16 + lr;
                int off = (row * 1536 + (kk + lk) * 2) ^ ((row & 7) << 4);
                a[mi] = *(const bf16x8*)(smem + 32768 + off);
            }
#pragma unroll
            for (int ni = 0; ni < 4; ni++) {
                int n = c0 + ni * 16 + lr;
                b[ni] = *(const bf16x8*)(w2base + (size_t)n * 768 + kk + lk);
            }
#pragma unroll
            for (int mi = 0; mi < 2; mi++)
#pragma unroll
                for (int ni = 0; ni < 4; ni++)
                    acc2[mi][ni] = __builtin_amdgcn_mfma_f32_16x16x32_bf16(
                        a[mi], b[ni], acc2[mi][ni], 0, 0, 0);
        }
        // epilogue: out[token] += gate * (O + b2)
        float b2v[4];
#pragma unroll
        for (int ni = 0; ni < 4; ni++) b2v[ni] = b2[e * 512 + c0 + ni * 16 + lr];
#pragma unroll
        for (int mi = 0; mi < 2; mi++) {
#pragma unroll
            for (int r = 0; r < 4; r++) {
                int row  = mi * 16 + (lane >> 4) * 4 + r;
                int slot = row0 + row;
                if (slot < cnt) {
                    int   tok = tokenlist[eT + slot];
                    float g   = gatelist[eT + slot];
                    float* orow = out + (size_t)tok * 512 + c0 + lr;
#pragma unroll
                    for (int ni = 0; ni < 4; ni++)
                        atomicAdd(orow + ni * 16, (acc2[mi][ni][r] + b2v[ni]) * g);
                }
            }
        }
    }
}

extern "C" void kernel_launch(void* const* d_in, const int* in_sizes, int n_in,
                              void* d_out, int out_size, void* d_ws, size_t ws_size,
                              hipStream_t stream) {
    const float* x  = (const float*)d_in[0];   // [8,2048,512]
    const float* Wg = (const float*)d_in[1];   // [512,8]
    const float* bg = (const float*)d_in[2];   // [8]
    const float* W1 = (const float*)d_in[3];   // [8,512,768]
    const float* b1 = (const float*)d_in[4];   // [8,768]
    const float* W2 = (const float*)d_in[5];   // [8,768,512]
    const float* b2 = (const float*)d_in[6];   // [8,512]
    float* out = (float*)d_out;                // [8,2048,512] fp32

    char* ws = (char*)d_ws;
    int*   counts    = (int*)(ws + 0);                    // 8 ints
    int*   tokenlist = (int*)(ws + 1024);                 // 8*16384 int
    float* gatelist  = (float*)(ws + 1024 + 524288);      // 8*16384 f32
    u16*   xb        = (u16*)(ws + 1049600);              // 16384*512 bf16
    u16*   W1t       = (u16*)(ws + 17826816);             // [8][768][512] bf16
    u16*   W2t       = (u16*)(ws + 24118272);             // [8][512][768] bf16
    (void)in_sizes; (void)n_in; (void)ws_size;

    hipMemsetAsync(d_out, 0, (size_t)out_size * sizeof(float), stream);
    hipMemsetAsync(counts, 0, 32, stream);

    cvt_x_kernel<<<2048, 256, 0, stream>>>(x, xb, (8 * 2048 * 512) / 4);
    transpose_cvt_kernel<<<dim3(24, 16, 8), 256, 0, stream>>>(W1, W1t, 512, 768);
    transpose_cvt_kernel<<<dim3(16, 24, 8), 256, 0, stream>>>(W2, W2t, 768, 512);
    router_kernel<<<128, 128, 0, stream>>>(x, Wg, bg, counts, tokenlist, gatelist);
    expert_kernel<<<4096, 512, 0, stream>>>(xb, W1t, W2t, b1, b2,
                                            counts, tokenlist, gatelist, out);
}

// Round 3
// 431.063 us; speedup vs baseline: 1.0548x; 1.0548x over previous
//
#include <hip/hip_runtime.h>
#include <math.h>
#include <stdint.h>

typedef unsigned short u16;
typedef unsigned int u32;
typedef __attribute__((ext_vector_type(8))) short bf16x8;   // 8 bf16 (4 VGPRs)
typedef __attribute__((ext_vector_type(4))) float f32x4;    // MFMA C/D

#define T_TOK 16384
#define NEXP 8
#define HROWS 33792   // 32768 + 8*128  (worst-case padded rows)
#define ROWT 264      // HROWS/128 row tiles

__device__ __forceinline__ u16 f2bf(float f) {
    union { float f; unsigned u; } v; v.f = f;
    unsigned u = v.u;
    return (u16)((u + 0x7fffu + ((u >> 16) & 1u)) >> 16);   // RNE
}

// async global->LDS, 16B per lane. LDS dest must be wave-uniform base + lane*16.
__device__ __forceinline__ void gload16(const void* g, void* l) {
    __builtin_amdgcn_global_load_lds(
        (const __attribute__((address_space(1))) u32*)(unsigned long long)(uintptr_t)g,
        (__attribute__((address_space(3))) u32*)(unsigned int)(uintptr_t)l,
        16, 0, 0);
}

__device__ __forceinline__ double shfl_xor_dbl(double v, int m) {
    union { double d; int i[2]; } u; u.d = v;
    u.i[0] = __shfl_xor(u.i[0], m, 64);
    u.i[1] = __shfl_xor(u.i[1], m, 64);
    return u.d;
}

// ------------- weights: [Z][R][C] f32 -> [Z][C][R] bf16 (transpose+convert) -------------
__global__ void transpose_cvt_kernel(const float* __restrict__ src, u16* __restrict__ dst,
                                     int R, int C) {
    __shared__ float tile[32][33];
    int e  = blockIdx.z;
    int c0 = blockIdx.x * 32, r0 = blockIdx.y * 32;
    int tx = threadIdx.x & 31, ty = threadIdx.x >> 5;   // ty in 0..7
    const float* s = src + (size_t)e * R * C;
#pragma unroll
    for (int i = 0; i < 32; i += 8)
        tile[ty + i][tx] = s[(size_t)(r0 + ty + i) * C + (c0 + tx)];
    __syncthreads();
    u16* d = dst + (size_t)e * R * C;
#pragma unroll
    for (int i = 0; i < 32; i += 8)
        d[(size_t)(c0 + ty + i) * R + (r0 + tx)] = f2bf(tile[tx][ty + i]);
}

// ------ router: scores (fp64, K split 2-way), top-2 gates, lists; also emits xb (bf16 x) ------
// 512 blocks x 64 threads; lane = (token 0..31, khalf 0..1)
__global__ void router_kernel(const float* __restrict__ x, const float* __restrict__ Wg,
                              const float* __restrict__ bg, int* __restrict__ counts,
                              int* __restrict__ tokenlist, float* __restrict__ gatelist,
                              u16* __restrict__ xb) {
    __shared__ float wg[512 * 8];
    int tid = threadIdx.x;                       // 64
    for (int i = tid; i < 1024; i += 64)
        ((float4*)wg)[i] = ((const float4*)Wg)[i];
    __syncthreads();

    int lane = tid;
    int tl = lane & 31, kh = lane >> 5;
    int t = blockIdx.x * 32 + tl;
    const float* xr = x  + (size_t)t * 512 + kh * 256;
    u16*       xrow = xb + (size_t)t * 512 + kh * 256;

    double acc[8];
#pragma unroll
    for (int j = 0; j < 8; j++) acc[j] = 0.0;
    for (int k = 0; k < 256; k += 4) {
        float4 v = *(const float4*)(xr + k);
        ushort4 o;
        o.x = f2bf(v.x); o.y = f2bf(v.y); o.z = f2bf(v.z); o.w = f2bf(v.w);
        *(ushort4*)(xrow + k) = o;
        float vv[4] = { v.x, v.y, v.z, v.w };
#pragma unroll
        for (int q = 0; q < 4; q++) {
#pragma unroll
            for (int j = 0; j < 8; j++)
                acc[j] += (double)vv[q] * (double)wg[(kh * 256 + k + q) * 8 + j];
        }
    }
#pragma unroll
    for (int j = 0; j < 8; j++) acc[j] += shfl_xor_dbl(acc[j], 32);

    double s[8];
#pragma unroll
    for (int j = 0; j < 8; j++) s[j] = acc[j] + (double)bg[j];
    int i0 = 0;
#pragma unroll
    for (int j = 1; j < 8; j++) if (s[j] > s[i0]) i0 = j;
    int i1 = (i0 == 0) ? 1 : 0;
#pragma unroll
    for (int j = 0; j < 8; j++) if (j != i0 && s[j] > s[i1]) i1 = j;
    float d  = expf((float)(s[i1] - s[i0]));
    float g0 = 1.f / (1.f + d);
    float g1 = d / (1.f + d);

    unsigned long long lt = (1ull << lane) - 1ull;
    for (int j = 0; j < NEXP; j++) {
#pragma unroll
        for (int p = 0; p < 2; p++) {
            int   ej = p ? i1 : i0;
            float gj = p ? g1 : g0;
            unsigned long long m = __ballot(kh == 0 && ej == j);
            if (m) {
                int leader = __ffsll(m) - 1;
                int base = 0;
                if (lane == leader) base = atomicAdd(&counts[j], __popcll(m));
                base = __shfl(base, leader);
                if (kh == 0 && ej == j) {
                    int slot = base + __popcll(m & lt);
                    tokenlist[j * T_TOK + slot] = t;
                    gatelist [j * T_TOK + slot] = gj;
                }
            }
        }
    }
}

// ------- scan: padded prefix offsets po[e] (tile-aligned expert regions), po[8]=total -------
__global__ void scan_kernel(const int* __restrict__ counts, int* __restrict__ po) {
    if (threadIdx.x == 0) {
        int s = 0;
        for (int e = 0; e < NEXP; e++) {
            po[e] = s;
            s += (counts[e] + 127) & ~127;
        }
        po[NEXP] = s;
    }
}

// ---------------- m97-style 128x128 GEMM, BK=64, 4 waves, global_load_lds staging ----------------
// PASS1: C = gathered xb @ W1t  -> GELU -> H (bf16, coalesced via LDS bounce)
// PASS2: C = H @ W2t -> (+b2)*gate -> atomicAdd scatter into out
template<int PASS>
__global__ __launch_bounds__(256) void moe_gemm(
    const u16* __restrict__ A, const u16* __restrict__ W,
    const float* __restrict__ bias,
    const int* __restrict__ counts, const int* __restrict__ po,
    const int* __restrict__ tokenlist, const float* __restrict__ gatelist,
    u16* __restrict__ Hout, float* __restrict__ out)
{
    constexpr int N = (PASS == 1) ? 768 : 512;
    constexpr int K = (PASS == 1) ? 512 : 768;

    __shared__ __align__(16) char smem[32768];   // As(16K)+Bs(16K); reused as epilogue bounce
    __shared__ int   tokrow[128];
    __shared__ float gaterow[128];
    __shared__ int   spo[9];

    int tid = threadIdx.x;
    int rt  = blockIdx.x % ROWT;      // adjacent blocks share the B panel
    int ct  = blockIdx.x / ROWT;
    int row0 = rt * 128;

    if (tid < 9) spo[tid] = po[tid];
    __syncthreads();
    if (row0 >= spo[8]) return;
    int e = 0;
    while (row0 >= spo[e + 1]) e++;
    int lr0 = row0 - spo[e];
    int cnt = counts[e];
    if (tid < 128) {
        int slot = lr0 + tid;
        int cl   = slot < cnt ? slot : cnt - 1;
        tokrow[tid]  = tokenlist[e * T_TOK + cl];
        gaterow[tid] = gatelist[e * T_TOK + cl];
    }
    __syncthreads();

    int n0 = ct * 128;
    char* As = smem;
    char* Bs = smem + 16384;

    // staging source pointers: dest chunk (iss*256+tid) is linear; source column is
    // XOR-swizzled so that swizzled LDS reads below see the un-swizzled element.
    const u16* aptr[4];
    const u16* bptr[4];
    const u16* wbase = W + (size_t)e * ((size_t)N * K);
#pragma unroll
    for (int iss = 0; iss < 4; iss++) {
        int chunk = iss * 256 + tid;
        int row   = chunk >> 3;
        int c16   = (chunk & 7) ^ (row & 7);
        if (PASS == 1)
            aptr[iss] = A + (size_t)tokrow[row] * K + c16 * 8;
        else
            aptr[iss] = A + (size_t)(row0 + row) * K + c16 * 8;
        bptr[iss] = wbase + (size_t)(n0 + row) * K + c16 * 8;
    }

    int lane = tid & 63, w = tid >> 6;
    int wr = w >> 1, wc = w & 1;                  // 2x2 waves, 64x64 each
    int lr = lane & 15, hk = lane >> 4;

    f32x4 acc[4][4];
#pragma unroll
    for (int mi = 0; mi < 4; mi++)
#pragma unroll
        for (int ni = 0; ni < 4; ni++)
            acc[mi][ni] = (f32x4){0.f, 0.f, 0.f, 0.f};

    for (int kk = 0; kk < K; kk += 64) {
#pragma unroll
        for (int iss = 0; iss < 4; iss++) {
            gload16(aptr[iss] + kk, As + (iss * 256 + tid) * 16);
            gload16(bptr[iss] + kk, Bs + (iss * 256 + tid) * 16);
        }
        __syncthreads();
#pragma unroll
        for (int ks = 0; ks < 2; ks++) {
            bf16x8 af[4], bfr[4];
#pragma unroll
            for (int mi = 0; mi < 4; mi++) {
                int row = wr * 64 + mi * 16 + lr;
                af[mi] = *(const bf16x8*)(As + row * 128 + (((ks * 4 + hk) ^ (row & 7)) * 16));
            }
#pragma unroll
            for (int ni = 0; ni < 4; ni++) {
                int row = wc * 64 + ni * 16 + lr;
                bfr[ni] = *(const bf16x8*)(Bs + row * 128 + (((ks * 4 + hk) ^ (row & 7)) * 16));
            }
#pragma unroll
            for (int mi = 0; mi < 4; mi++)
#pragma unroll
                for (int ni = 0; ni < 4; ni++)
                    acc[mi][ni] = __builtin_amdgcn_mfma_f32_16x16x32_bf16(
                        af[mi], bfr[ni], acc[mi][ni], 0, 0, 0);
        }
        __syncthreads();
    }

    if (PASS == 1) {
        // bias + exact GELU -> LDS bounce (bf16 [128][128] = 128 rows x 256B) -> coalesced stores
#pragma unroll
        for (int ni = 0; ni < 4; ni++) {
            int lcol = wc * 64 + ni * 16 + lr;
            float bb = bias[e * N + n0 + lcol];
#pragma unroll
            for (int mi = 0; mi < 4; mi++) {
#pragma unroll
                for (int r = 0; r < 4; r++) {
                    int row = wr * 64 + mi * 16 + hk * 4 + r;
                    float h = acc[mi][ni][r] + bb;
                    float g = 0.5f * h * (1.f + erff(h * 0.70710678118654752f));
                    *(u16*)(smem + row * 256 + lcol * 2) = f2bf(g);
                }
            }
        }
        __syncthreads();
        // 2048 chunks of 16B: 16 chunks per row (256B), 128 rows  [fixed from 1024-chunk bug]
#pragma unroll
        for (int iss = 0; iss < 8; iss++) {
            int chunk = iss * 256 + tid;
            int row = chunk >> 4, c16 = chunk & 15;
            uint4 v = *(const uint4*)(smem + row * 256 + c16 * 16);
            *(uint4*)(Hout + (size_t)(row0 + row) * 768 + n0 + c16 * 8) = v;
        }
    } else {
        // (+b2) * gate -> atomic scatter
#pragma unroll
        for (int ni = 0; ni < 4; ni++) {
            int gcol = n0 + wc * 64 + ni * 16 + lr;
            float bb = bias[e * N + gcol];
#pragma unroll
            for (int mi = 0; mi < 4; mi++) {
#pragma unroll
                for (int r = 0; r < 4; r++) {
                    int row  = wr * 64 + mi * 16 + hk * 4 + r;
                    int slot = lr0 + row;
                    if (slot < cnt) {
                        int   tok = tokrow[row];
                        float g   = gaterow[row];
                        atomicAdd(out + (size_t)tok * 512 + gcol,
                                  (acc[mi][ni][r] + bb) * g);
                    }
                }
            }
        }
    }
}

extern "C" void kernel_launch(void* const* d_in, const int* in_sizes, int n_in,
                              void* d_out, int out_size, void* d_ws, size_t ws_size,
                              hipStream_t stream) {
    const float* x  = (const float*)d_in[0];   // [8,2048,512]
    const float* Wg = (const float*)d_in[1];   // [512,8]
    const float* bg = (const float*)d_in[2];   // [8]
    const float* W1 = (const float*)d_in[3];   // [8,512,768]
    const float* b1 = (const float*)d_in[4];   // [8,768]
    const float* W2 = (const float*)d_in[5];   // [8,768,512]
    const float* b2 = (const float*)d_in[6];   // [8,512]
    float* out = (float*)d_out;                // [8,2048,512] fp32

    char* ws = (char*)d_ws;
    int*   counts    = (int*)(ws + 0);                    // 8 ints
    int*   po        = (int*)(ws + 256);                  // 9 ints
    int*   tokenlist = (int*)(ws + 1024);                 // 8*16384 int   (512 KB)
    float* gatelist  = (float*)(ws + 526336);             // 8*16384 f32   (512 KB)
    u16*   xb        = (u16*)(ws + 1052672);              // 16384*512 bf16 (16 MB)
    u16*   W1t       = (u16*)(ws + 17829888);             // [8][768][512] bf16 (6 MB)
    u16*   W2t       = (u16*)(ws + 24121344);             // [8][512][768] bf16 (6 MB)
    u16*   H         = (u16*)(ws + 30412800);             // [33792][768] bf16 (51.9 MB)
    (void)in_sizes; (void)n_in; (void)ws_size;

    hipMemsetAsync(d_out, 0, (size_t)out_size * sizeof(float), stream);
    hipMemsetAsync(counts, 0, 32, stream);

    router_kernel<<<512, 64, 0, stream>>>(x, Wg, bg, counts, tokenlist, gatelist, xb);
    transpose_cvt_kernel<<<dim3(24, 16, 8), 256, 0, stream>>>(W1, W1t, 512, 768);
    transpose_cvt_kernel<<<dim3(16, 24, 8), 256, 0, stream>>>(W2, W2t, 768, 512);
    scan_kernel<<<1, 64, 0, stream>>>(counts, po);

    moe_gemm<1><<<6 * ROWT, 256, 0, stream>>>(xb, W1t, b1, counts, po,
                                              tokenlist, gatelist, H, nullptr);
    moe_gemm<2><<<4 * ROWT, 256, 0, stream>>>(H, W2t, b2, counts, po,
                                              tokenlist, gatelist, nullptr, out);
}